// Round 12
// baseline (335.824 us; speedup 1.0000x reference)
//
#include <hip/hip_runtime.h>
#include <hip/hip_bf16.h>
#include <math.h>

// Problem constants (B=2048, D=512, C=100000)
constexpr int Bq = 2048;
constexpr int Dq = 512;
constexpr int Cq = 100000;
constexpr int NPAD = 100096;     // 782 * 128

constexpr float SCALE = 64.0f;
constexpr float COS_M = 0.8775825618903728f;   // cos(0.5)
constexpr float SIN_M = 0.479425538604203f;    // sin(0.5)
constexpr float THR   = -0.8775825618903728f;  // cos(pi - 0.5)
constexpr float MM    = 0.2397127693021015f;   // sin(pi - 0.5) * 0.5

typedef __attribute__((ext_vector_type(8))) __bf16 bf16x8;
typedef __attribute__((ext_vector_type(4))) float f32x4;

typedef const __attribute__((address_space(1))) unsigned int guint;
typedef __attribute__((address_space(3))) unsigned int suint;

__device__ __forceinline__ void gload_lds16(const unsigned short* g, unsigned short* lds)
{
    __builtin_amdgcn_global_load_lds((guint*)g, (suint*)lds, 16, 0, 0);
}

__device__ __forceinline__ unsigned int pack_bf16x2(float lo, float hi)
{
    __hip_bfloat16 h0 = __float2bfloat16(lo);
    __hip_bfloat16 h1 = __float2bfloat16(hi);
    return ((unsigned int)(*(unsigned short*)&h1) << 16) |
           (unsigned int)(*(unsigned short*)&h0);
}

// ---------------------------------------------------------------------------
// Row L2-normalize fp32 [*][512] -> bf16, wave-per-row, float4 loads,
// pure shuffle reduce. 4 rows per 256-thread block. Pad rows write zeros.
// ---------------------------------------------------------------------------
__global__ __launch_bounds__(256) void normalize_rows_kernel(
    const float* __restrict__ in, unsigned short* __restrict__ out, int nrows)
{
    const int w = threadIdx.x >> 6, lane = threadIdx.x & 63;
    const int row = blockIdx.x * 4 + w;
    float4 a = {0.f, 0.f, 0.f, 0.f}, b = a;
    if (row < nrows) {
        const float4* src = reinterpret_cast<const float4*>(in + (size_t)row * Dq);
        a = src[lane];
        b = src[lane + 64];
    }
    float ss = a.x * a.x + a.y * a.y + a.z * a.z + a.w * a.w
             + b.x * b.x + b.y * b.y + b.z * b.z + b.w * b.w;
    #pragma unroll
    for (int off = 32; off > 0; off >>= 1) ss += __shfl_down(ss, off);
    ss = __shfl(ss, 0);
    const float invn = 1.0f / fmaxf(sqrtf(ss), 1e-12f);

    uint2* out64 = reinterpret_cast<uint2*>(out + (size_t)row * Dq);
    uint2 pa, pb;
    pa.x = pack_bf16x2(a.x * invn, a.y * invn);
    pa.y = pack_bf16x2(a.z * invn, a.w * invn);
    pb.x = pack_bf16x2(b.x * invn, b.y * invn);
    pb.y = pack_bf16x2(b.z * invn, b.w * invn);
    out64[lane] = pa;
    out64[lane + 64] = pb;
}

// ---------------------------------------------------------------------------
// 128x128 GEMM, BK=32, 16 kt, 4 waves (2M x 2N, 64x64 per wave),
// LDS: K-loop 2 x (A 8KB + B 8KB) = 32 KB dbuf; epilogue overlay [64][132]
// f32 = 33.8 KB -> block LDS 33792 B -> 4 BLOCKS/CU (4 waves/SIMD).
// ROUND 12: occupancy 2x is the single lever (R8 profile: nothing >50% busy,
// VGPR=88, LDS-bound at 2 blocks -> latency-bound). Whole-buffer-granularity
// 2-deep pipeline (no partial-slab staging -> no R10-style races):
//   prologue: stage kt0 -> buf0, kt1 -> buf1 (4 issues each); vmcnt(4); bar
//   per kt:   read 8 frags from cb; lgkm(0); bar;
//             if kt<14 stage kt+2 -> cb (4 issues);
//             16 MFMA (setprio); vmcnt(kt<14 ? 4 : 0); bar
// Ledger: at each gate the 4 newest in-flight loads are exactly kt+2's
// issues -> kt+1 fully landed before its reads. Stage->cb is issued after
// the post-read barrier (all waves hold kt's frags in regs).
// T1 XCD swizzle; T2 involution swizzle (chunk ^ (row>>1)&3 on 64B rows);
// T5 setprio; swapped-operand MFMA; two-pass line-aligned nt epilogue.
// ---------------------------------------------------------------------------
__global__ __launch_bounds__(256, 4) void arc_gemm_kernel(
    const unsigned short* __restrict__ A,
    const unsigned short* __restrict__ Bn,
    const int* __restrict__ labels,
    float* __restrict__ out)
{
    extern __shared__ unsigned short lds[];   // 33792 B

    // T1: XCD-aware bijective swizzle (12512 = 8 * 1564 exact)
    const int cpx = (int)gridDim.x >> 3;
    const int bid = ((int)blockIdx.x & 7) * cpx + ((int)blockIdx.x >> 3);
    const int tm = bid & 15;         // 16 m-tiles share one B-strip per XCD
    const int tn = bid >> 4;
    const int m0 = tm * 128, n0 = tn * 128;

    const int t = threadIdx.x;
    const int w = t >> 6, lane = t & 63;
    const int wr = (w >> 1) * 64;    // wave M (emb) origin
    const int wc = (w & 1) * 64;     // wave N (class) origin
    const int fr = lane & 15, kg = lane >> 4;
    const int cfrag = (kg ^ ((fr >> 1) & 3)) * 8;   // swizzled chunk (elems)

    // staging: one issue = 256 thr x 16B = 4KB = 64 rows x 64B.
    // thread t: row trow = t>>2 (0..63), chunk t&3, src chunk pre-swizzled.
    const int trow = t >> 2;
    const int sch = ((t & 3) ^ ((trow >> 1) & 3)) * 8;
    const unsigned short* gA = A  + (size_t)(m0 + trow) * Dq + sch;
    const unsigned short* gB = Bn + (size_t)(n0 + trow) * Dq + sch;
    const int dst = t * 8;   // linear LDS dest within issue (= tid*16B)

#define STAGE_A(buf, u, kts) gload_lds16(gA + (size_t)(u) * 64 * Dq + (kts) * 32, \
                                         &lds[(buf) * 8192 + (u) * 2048 + dst])
#define STAGE_B(buf, u, kts) gload_lds16(gB + (size_t)(u) * 64 * Dq + (kts) * 32, \
                                         &lds[(buf) * 8192 + 4096 + (u) * 2048 + dst])
#define BARRIER() do { __builtin_amdgcn_sched_barrier(0); __builtin_amdgcn_s_barrier(); } while (0)

    f32x4 acc[4][4];
    #pragma unroll
    for (int i = 0; i < 4; ++i)
        #pragma unroll
        for (int j = 0; j < 4; ++j) acc[i][j] = {0.f, 0.f, 0.f, 0.f};

    // Prologue: kt0 -> buf0, kt1 -> buf1
    STAGE_A(0, 0, 0); STAGE_A(0, 1, 0); STAGE_B(0, 0, 0); STAGE_B(0, 1, 0);
    STAGE_A(1, 0, 1); STAGE_A(1, 1, 1); STAGE_B(1, 0, 1); STAGE_B(1, 1, 1);
    asm volatile("s_waitcnt vmcnt(4)" ::: "memory");   // kt0 landed
    __builtin_amdgcn_s_barrier();

    const int arow = (wr + fr) * 32 + cfrag;          // A frag base (quad 0)
    const int brow = 4096 + (wc + fr) * 32 + cfrag;   // B frag base (ni 0)

    #pragma unroll
    for (int kt = 0; kt < 16; ++kt) {
        const int cb = kt & 1;
        const int cbo = cb * 8192;
        bf16x8 afr[4], bfr[4];
        #pragma unroll
        for (int mi = 0; mi < 4; ++mi)
            afr[mi] = *reinterpret_cast<const bf16x8*>(&lds[cbo + arow + mi * 512]);
        #pragma unroll
        for (int ni = 0; ni < 4; ++ni)
            bfr[ni] = *reinterpret_cast<const bf16x8*>(&lds[cbo + brow + ni * 512]);
        asm volatile("s_waitcnt lgkmcnt(0)" ::: "memory");  // frags in regs
        BARRIER();                                          // all waves done with cb
        if (kt < 14) {   // restage same buffer with kt+2
            STAGE_A(cb, 0, kt + 2); STAGE_A(cb, 1, kt + 2);
            STAGE_B(cb, 0, kt + 2); STAGE_B(cb, 1, kt + 2);
        }
        __builtin_amdgcn_s_setprio(1);
        #pragma unroll
        for (int mi = 0; mi < 4; ++mi)
            #pragma unroll
            for (int ni = 0; ni < 4; ++ni)
                acc[mi][ni] = __builtin_amdgcn_mfma_f32_16x16x32_bf16(
                    bfr[ni], afr[mi], acc[mi][ni], 0, 0, 0);   // swapped operands
        __builtin_amdgcn_s_setprio(0);
        if (kt < 14) asm volatile("s_waitcnt vmcnt(4)" ::: "memory"); // kt+1 landed
        else         asm volatile("s_waitcnt vmcnt(0)" ::: "memory");
        BARRIER();
    }

    // ---- Epilogue: two passes of [64][132] f32 overlay -> line-aligned nt
    // stores (8 rows x 512B per instruction). acc mapping (swapped operands):
    // emb row = wr + mi*16 + fr, class col = wc + ni*16 + kg*4 + reg.
    float* lf = reinterpret_cast<float*>(lds);
    #pragma unroll
    for (int pass = 0; pass < 2; ++pass) {
        if ((w >> 1) == pass) {   // waves owning rows [pass*64, pass*64+64)
            #pragma unroll
            for (int mi = 0; mi < 4; ++mi) {
                const int lrow = mi * 16 + fr;            // 0..63
                const int lab = labels[m0 + pass * 64 + lrow];
                #pragma unroll
                for (int ni = 0; ni < 4; ++ni) {
                    const int col0 = wc + ni * 16 + kg * 4;
                    const int gcol0 = n0 + col0;
                    f32x4 v = acc[mi][ni];
                    #pragma unroll
                    for (int r = 0; r < 4; ++r) {
                        if (gcol0 + r == lab) {
                            float c = v[r];
                            float sine = sqrtf(fmaxf(1.0f - c * c, 0.0f));
                            float phi = c * COS_M - sine * SIN_M;
                            v[r] = (c > THR) ? phi : (c - MM);
                        }
                    }
                    v *= SCALE;
                    *reinterpret_cast<f32x4*>(&lf[lrow * 132 + col0]) = v;
                }
            }
        }
        __syncthreads();
        // read back: each instruction = 8 rows x (32 lanes x 16B = 512B/row)
        const int cc = t & 31, rh = t >> 5;   // rh 0..7
        #pragma unroll
        for (int s = 0; s < 8; ++s) {
            const int lrow = s * 8 + rh;
            f32x4 v = *reinterpret_cast<const f32x4*>(&lf[lrow * 132 + cc * 4]);
            const int gcol0 = n0 + cc * 4;
            if (gcol0 < Cq)
                __builtin_nontemporal_store(
                    v, reinterpret_cast<f32x4*>(
                        out + (size_t)(m0 + pass * 64 + lrow) * Cq + gcol0));
        }
        __syncthreads();   // reads done before next pass overwrites lf
    }
#undef STAGE_A
#undef STAGE_B
#undef BARRIER
}

extern "C" void kernel_launch(void* const* d_in, const int* in_sizes, int n_in,
                              void* d_out, int out_size, void* d_ws, size_t ws_size,
                              hipStream_t stream)
{
    const float* emb    = (const float*)d_in[0];
    const int*   labels = (const int*)d_in[1];
    const float* weight = (const float*)d_in[2];
    float* out = (float*)d_out;

    unsigned short* Abf = (unsigned short*)d_ws;             // 2 MB
    unsigned short* Bbf = Abf + (size_t)Bq * Dq;             // 102.5 MB

    normalize_rows_kernel<<<Bq / 4, 256, 0, stream>>>(emb, Abf, Bq);
    normalize_rows_kernel<<<NPAD / 4, 256, 0, stream>>>(weight, Bbf, Cq);
    arc_gemm_kernel<<<16 * (NPAD / 128), 256, 33792, stream>>>(Abf, Bbf, labels, out);
}